// Round 5
// baseline (541.239 us; speedup 1.0000x reference)
//
#include <hip/hip_runtime.h>
#include <hip/hip_bf16.h>

#define NBATCH 2
#define NBB    16
#define NIC    8
#define NOC    16
#define NQ     30
#define NMM    6
#define NU     5
#define NV     5
#define NNC    25   // NU*NV
#define CG     4    // c-groups (one per wave)
#define CPG    2    // channels per group (CG*CPG == NIC)

__global__ __launch_bounds__(256, 2) void lbc_main(
    const float* __restrict__ x_re,   const float* __restrict__ x_im,
    const float* __restrict__ lnAlpha,const float* __restrict__ Phi,
    const float* __restrict__ lnTau,  const float* __restrict__ Psi,
    const float* __restrict__ pAlpha_re, const float* __restrict__ pAlpha_im,
    const float* __restrict__ pPhi_re,   const float* __restrict__ pPhi_im,
    const float* __restrict__ pTau_re,   const float* __restrict__ pTau_im,
    const float* __restrict__ pPsi_re,   const float* __restrict__ pPsi_im,
    const float* __restrict__ F_re,      const float* __restrict__ F_im,
    const float* __restrict__ coeffs,
    float* __restrict__ out)
{
    // 32 KiB LDS, time-shared: phase 1 = Wp[NIC][NNC][NOC] float2 (25.6 KiB),
    // phase 2 = reduction buffer [CG][NOC][64] float2 (32 KiB).
    __shared__ __align__(16) char smem[32768];
    float2* const Wp = reinterpret_cast<float2*>(smem);

    // Block identity: bid = ((b*NQ + q)*NMM + m)*4 + qt
    const int bid = blockIdx.x;
    const int qt  = bid & 3;                 // y-quarter of the 16x16 tile
    const int bqm = bid >> 2;
    const int m   = bqm % NMM;
    const int q   = (bqm / NMM) % NQ;
    const int b   = bqm / (NMM * NQ);
    const int qm  = q * NMM + m;

    // ---- Stage W' = collect_weights(coeffs) * F[qm] into LDS ----
    for (int idx = threadIdx.x; idx < NIC * NNC * NOC; idx += 256) {
        const int o = idx & (NOC - 1);
        const int n = (idx >> 4) % NNC;
        const int c = idx / (NOC * NNC);
        float wr, wi;
        if (n < 12) {
            wr = coeffs[(c * NNC + (23 - 2 * n)) * NOC + o];
            wi = coeffs[(c * NNC + (24 - 2 * n)) * NOC + o];
        } else if (n == 12) {
            wr = coeffs[(c * NNC + 0) * NOC + o];
            wi = 0.0f;
        } else {
            wr = coeffs[(c * NNC + (2 * n - 25)) * NOC + o];
            wi = coeffs[(c * NNC + (2 * n - 24)) * NOC + o];
        }
        const float fr = F_re[qm * NNC + n];
        const float fi = F_im[qm * NNC + n];
        Wp[idx] = make_float2(wr * fr - wi * fi, wr * fi + wi * fr);
    }
    __syncthreads();

    // ---- Thread identity: wave = c-group, lane = point in quarter-tile ----
    const int tid = threadIdx.x;
    const int cg  = tid >> 6;                // 0..3 (wave id)
    const int p   = tid & 63;
    const int y   = qt * 4 + (p >> 4);
    const int x   = p & 15;
    const int pt  = (b * NBB + y) * NBB + x; // point index

    // ---- Block-uniform basis params (uniform addresses -> scalar regs) ----
    const float pAre = pAlpha_re[qm], pAim = pAlpha_im[qm];
    const float pPre = pPhi_re[m],    pPim = pPhi_im[m];
    float pTre[NU], pTim[NU], pSre[NV], pSim[NV];
    #pragma unroll
    for (int u = 0; u < NU; ++u) { pTre[u] = pTau_re[qm * NU + u]; pTim[u] = pTau_im[qm * NU + u]; }
    #pragma unroll
    for (int v = 0; v < NV; ++v) { pSre[v] = pPsi_re[m * NV + v]; pSim[v] = pPsi_im[m * NV + v]; }

    // ---- Per-point inputs for this wave's two channels (float2 = 8B/lane) ----
    const int p2 = pt * (NIC / 2) + cg;      // float2 index: channels 2cg, 2cg+1
    const float2 xr2 = reinterpret_cast<const float2*>(x_re)[p2];
    const float2 xi2 = reinterpret_cast<const float2*>(x_im)[p2];
    const float2 la2 = reinterpret_cast<const float2*>(lnAlpha)[p2];
    const float2 ph2 = reinterpret_cast<const float2*>(Phi)[p2];
    const float2 lt2 = reinterpret_cast<const float2*>(lnTau)[p2];
    const float2 ps2 = reinterpret_cast<const float2*>(Psi)[p2];

    float accr[NOC], acci[NOC];
    #pragma unroll
    for (int o = 0; o < NOC; ++o) { accr[o] = 0.0f; acci[o] = 0.0f; }

    #pragma unroll 1
    for (int cc = 0; cc < CPG; ++cc) {
        const int c = cg * CPG + cc;
        const float xr = cc ? xr2.y : xr2.x;
        const float xi = cc ? xi2.y : xi2.x;
        const float la = cc ? la2.y : la2.x;
        const float ph = cc ? ph2.y : ph2.x;
        const float lt = cc ? lt2.y : lt2.x;
        const float ps = cc ? ps2.y : ps2.x;

        // A = x * exp(la*pAlpha + ph*pPhi)
        const float ar = la * pAre + ph * pPre;
        const float ai = la * pAim + ph * pPim;
        const float ea = __expf(ar);
        const float er_ = ea * __cosf(ai);
        const float ei_ = ea * __sinf(ai);
        const float Are = xr * er_ - xi * ei_;
        const float Aim = xr * ei_ + xi * er_;

        // eu[u] = exp(lt * pTau[u]),  ev[v] = exp(ps * pPsi[v])
        float eur[NU], eui[NU], evr[NV], evi[NV];
        #pragma unroll
        for (int u = 0; u < NU; ++u) {
            const float rr = __expf(lt * pTre[u]);
            const float th = lt * pTim[u];
            eur[u] = rr * __cosf(th);
            eui[u] = rr * __sinf(th);
        }
        #pragma unroll
        for (int v = 0; v < NV; ++v) {
            const float rr = __expf(ps * pSre[v]);
            const float th = ps * pSim[v];
            evr[v] = rr * __cosf(th);
            evi[v] = rr * __sinf(th);
        }

        #pragma unroll
        for (int u = 0; u < NU; ++u) {
            const float gr = Are * eur[u] - Aim * eui[u];
            const float gi = Are * eui[u] + Aim * eur[u];
            #pragma unroll
            for (int v = 0; v < NV; ++v) {
                const float tr = gr * evr[v] - gi * evi[v];
                const float ti = gr * evi[v] + gi * evr[v];
                // W'[c][n][0..15]: 16 float2 = 8 x float4 (ds_read_b128 broadcast)
                const float4* w4 = reinterpret_cast<const float4*>(
                    Wp + ((c * NNC + u * NV + v) << 4));
                #pragma unroll
                for (int j = 0; j < 8; ++j) {
                    const float4 w = w4[j];
                    accr[2*j]   += tr * w.x - ti * w.y;
                    acci[2*j]   += tr * w.y + ti * w.x;
                    accr[2*j+1] += tr * w.z - ti * w.w;
                    acci[2*j+1] += tr * w.w + ti * w.z;
                }
            }
        }
    }

    // ---- Cross-wave reduction over c-groups (reuse smem) ----
    __syncthreads();                          // all Wp reads done
    float2* const red = reinterpret_cast<float2*>(smem);  // [CG][NOC][64]
    #pragma unroll
    for (int o = 0; o < NOC; ++o)
        red[(cg * NOC + o) * 64 + p] = make_float2(accr[o], acci[o]);
    __syncthreads();

    for (int i = tid; i < NOC * 64; i += 256) {
        const int pp = i & 63;
        const int o  = i >> 6;
        float2 s = red[(0 * NOC + o) * 64 + pp];
        #pragma unroll
        for (int g = 1; g < CG; ++g) {
            const float2 t = red[(g * NOC + o) * 64 + pp];
            s.x += t.x; s.y += t.y;
        }
        const int yy = qt * 4 + (pp >> 4);
        const int xx = pp & 15;
        const size_t oi = (((((size_t)b * NOC + o) * NQ + q) * NMM + m) * NBB + yy) * NBB + xx;
        reinterpret_cast<float2*>(out)[oi] = s;
    }
}

extern "C" void kernel_launch(void* const* d_in, const int* in_sizes, int n_in,
                              void* d_out, int out_size, void* d_ws, size_t ws_size,
                              hipStream_t stream) {
    const float* x_re      = (const float*)d_in[0];
    const float* x_im      = (const float*)d_in[1];
    const float* lnAlpha   = (const float*)d_in[2];
    const float* Phi       = (const float*)d_in[3];
    const float* lnTau     = (const float*)d_in[4];
    const float* Psi       = (const float*)d_in[5];
    const float* pAlpha_re = (const float*)d_in[6];
    const float* pAlpha_im = (const float*)d_in[7];
    const float* pPhi_re   = (const float*)d_in[8];
    const float* pPhi_im   = (const float*)d_in[9];
    const float* pTau_re   = (const float*)d_in[10];
    const float* pTau_im   = (const float*)d_in[11];
    const float* pPsi_re   = (const float*)d_in[12];
    const float* pPsi_im   = (const float*)d_in[13];
    const float* F_re      = (const float*)d_in[14];
    const float* F_im      = (const float*)d_in[15];
    const float* coeffs    = (const float*)d_in[16];
    float* out = (float*)d_out;

    dim3 grid(NBATCH * NQ * NMM * 4);   // 1440: (b,q,m) x 4 quarter-tiles
    dim3 block(256);                    // 4 c-group waves x 64 points
    lbc_main<<<grid, block, 0, stream>>>(
        x_re, x_im, lnAlpha, Phi, lnTau, Psi,
        pAlpha_re, pAlpha_im, pPhi_re, pPhi_im,
        pTau_re, pTau_im, pPsi_re, pPsi_im,
        F_re, F_im, coeffs, out);
}